// Round 1
// baseline (5493.571 us; speedup 1.0000x reference)
//
#include <hip/hip_runtime.h>
#include <hip/hip_bf16.h>
#include <math.h>

#define Dm   1024
#define Hh   16
#define DH   64
#define Sx   2048

// ---------------------------------------------------------------- reductions
__device__ __forceinline__ float wave_max(float v) {
#pragma unroll
    for (int o = 32; o > 0; o >>= 1) v = fmaxf(v, __shfl_xor(v, o, 64));
    return v;
}
__device__ __forceinline__ float wave_sum(float v) {
#pragma unroll
    for (int o = 32; o > 0; o >>= 1) v += __shfl_xor(v, o, 64);
    return v;
}
__device__ __forceinline__ float block_reduce_max(float v, volatile float* buf, int tid) {
    v = wave_max(v);
    __syncthreads();
    if ((tid & 63) == 0) buf[tid >> 6] = v;
    __syncthreads();
    return fmaxf(fmaxf(buf[0], buf[1]), fmaxf(buf[2], buf[3]));
}
__device__ __forceinline__ float block_reduce_sum(float v, volatile float* buf, int tid) {
    v = wave_sum(v);
    __syncthreads();
    if ((tid & 63) == 0) buf[tid >> 6] = v;
    __syncthreads();
    return buf[0] + buf[1] + buf[2] + buf[3];
}

// ---------------------------------------------------------------- LayerNorm
// one block per row of 1024; 256 threads, float4 each
__global__ __launch_bounds__(256) void ln_kernel(const float* __restrict__ x,
                                                 const float* __restrict__ g,
                                                 const float* __restrict__ b,
                                                 float* __restrict__ out) {
    int row = blockIdx.x;
    int tid = threadIdx.x;
    const float4* xr = (const float4*)(x + (size_t)row * Dm);
    float4 v = xr[tid];
    float s  = v.x + v.y + v.z + v.w;
    float ss = v.x * v.x + v.y * v.y + v.z * v.z + v.w * v.w;
    __shared__ float rbuf[8];
    s  = wave_sum(s);
    ss = wave_sum(ss);
    if ((tid & 63) == 0) { rbuf[tid >> 6] = s; rbuf[4 + (tid >> 6)] = ss; }
    __syncthreads();
    float mean = (rbuf[0] + rbuf[1] + rbuf[2] + rbuf[3]) * (1.0f / Dm);
    float msq  = (rbuf[4] + rbuf[5] + rbuf[6] + rbuf[7]) * (1.0f / Dm);
    float var  = msq - mean * mean;
    float rstd = 1.0f / sqrtf(var + 1e-5f);
    float4 gg = ((const float4*)g)[tid];
    float4 bb = ((const float4*)b)[tid];
    float4 o;
    o.x = (v.x - mean) * rstd * gg.x + bb.x;
    o.y = (v.y - mean) * rstd * gg.y + bb.y;
    o.z = (v.z - mean) * rstd * gg.z + bb.z;
    o.w = (v.w - mean) * rstd * gg.w + bb.w;
    ((float4*)(out + (size_t)row * Dm))[tid] = o;
}

// ---------------------------------------------------------------- sinusoidal PE (fp64 for exactness)
__global__ __launch_bounds__(256) void pe_kernel(float* __restrict__ pe) {
    int idx = blockIdx.x * 256 + threadIdx.x;   // Sx * 512 threads
    int r = idx >> 9;
    int t = idx & 511;
    double div = exp((double)(2 * t) * (-9.210340371976184 / 1024.0)); // ln(10000)
    double ang = (double)r * div;
    pe[(size_t)r * Dm + 2 * t]     = (float)sin(ang);
    pe[(size_t)r * Dm + 2 * t + 1] = (float)cos(ang);
}

// ---------------------------------------------------------------- SGEMM 128x128x8, 8x8/thread
// C[M,N] = A[M,K] @ B[K,N] (+bias).  M%128==0, N%128==0, K%8==0.
__global__ __launch_bounds__(256) void sgemm_kernel(const float* __restrict__ A,
                                                    const float* __restrict__ B,
                                                    const float* __restrict__ bias,
                                                    float* __restrict__ C,
                                                    int M, int N, int K) {
    __shared__ float As[8][128];
    __shared__ float Bs[8][128];
    int tid = threadIdx.x;
    int bn = blockIdx.x * 128;
    int bm = blockIdx.y * 128;
    int arow = tid >> 1, acol = (tid & 1) * 4;
    int brow = tid >> 5, bcol = (tid & 31) * 4;
    int tm = (tid >> 4) * 8, tn = (tid & 15) * 8;
    const float* Ap = A + (size_t)(bm + arow) * K + acol;
    const float* Bp = B + (size_t)brow * N + bn + bcol;
    float acc[8][8];
#pragma unroll
    for (int i = 0; i < 8; i++)
#pragma unroll
        for (int j = 0; j < 8; j++) acc[i][j] = 0.0f;

    for (int k0 = 0; k0 < K; k0 += 8) {
        float4 av = *(const float4*)(Ap + k0);
        float4 bv = *(const float4*)(Bp + (size_t)k0 * N);
        __syncthreads();
        As[acol + 0][arow] = av.x;
        As[acol + 1][arow] = av.y;
        As[acol + 2][arow] = av.z;
        As[acol + 3][arow] = av.w;
        *(float4*)&Bs[brow][bcol] = bv;
        __syncthreads();
#pragma unroll
        for (int kk = 0; kk < 8; kk++) {
            float a[8], bb[8];
            *(float4*)&a[0]  = *(const float4*)&As[kk][tm];
            *(float4*)&a[4]  = *(const float4*)&As[kk][tm + 4];
            *(float4*)&bb[0] = *(const float4*)&Bs[kk][tn];
            *(float4*)&bb[4] = *(const float4*)&Bs[kk][tn + 4];
#pragma unroll
            for (int i = 0; i < 8; i++)
#pragma unroll
                for (int j = 0; j < 8; j++) acc[i][j] += a[i] * bb[j];
        }
    }
    float bvreg[8];
#pragma unroll
    for (int j = 0; j < 8; j++) bvreg[j] = bias ? bias[bn + tn + j] : 0.0f;
#pragma unroll
    for (int i = 0; i < 8; i++) {
        float* crow = C + (size_t)(bm + tm + i) * N + bn + tn;
        float4 o0, o1;
        o0.x = acc[i][0] + bvreg[0]; o0.y = acc[i][1] + bvreg[1];
        o0.z = acc[i][2] + bvreg[2]; o0.w = acc[i][3] + bvreg[3];
        o1.x = acc[i][4] + bvreg[4]; o1.y = acc[i][5] + bvreg[5];
        o1.z = acc[i][6] + bvreg[6]; o1.w = acc[i][7] + bvreg[7];
        *(float4*)(crow)     = o0;
        *(float4*)(crow + 4) = o1;
    }
}

// ---------------------------------------------------------------- attention
// one block = (b, h, 4 query rows).  Relative shift (verified on S=4 example):
//   j <= i   : pos = raw[i,   S-1+j-i]
//   j == i+1 : pos = 0
//   j >= i+2 : pos = raw[i+1, j-i-2]      (needs query row i0+4 too)
__global__ __launch_bounds__(256) void attn_kernel(const float* __restrict__ q,
                                                   const float* __restrict__ k,
                                                   const float* __restrict__ v,
                                                   const float* __restrict__ p,
                                                   const float* __restrict__ ub,
                                                   const float* __restrict__ vbias,
                                                   float* __restrict__ head) {
    // U: first pos_raw[5][2048] (40KB); after combine re-used as probs sc[4][2048]
    // (0..8191) + partials (8192..9215). Aliasing is safe: all pos reads complete
    // before the first __syncthreads inside block_reduce_max.
    __shared__ float U[10240];
    __shared__ float qu[4][DH];
    __shared__ float qv[5][DH];
    __shared__ float rbuf[4];

    int tid = threadIdx.x;
    int blk = blockIdx.x;
    int qt = blk & 511;
    int h  = (blk >> 9) & 15;
    int b  = blk >> 13;
    int i0 = qt * 4;

    // load query fragments (+ biases)
    for (int idx = tid; idx < 9 * DH; idx += 256) {
        int r = idx >> 6, d = idx & 63;
        if (r < 4) {
            float qval = q[((size_t)(b * Sx + i0 + r)) * Dm + h * DH + d];
            qu[r][d] = qval + ub[h * DH + d];
        } else {
            int rr = r - 4;
            int i = i0 + rr;
            float qval = (i < Sx) ? q[((size_t)(b * Sx + i)) * Dm + h * DH + d] : 0.0f;
            qv[rr][d] = qval + vbias[h * DH + d];
        }
    }
    __syncthreads();

    // ---- content scores: cont[jt][qq] = qu[qq] . k_j , j = tid + jt*256
    float cont[8][4];
#pragma unroll
    for (int jt = 0; jt < 8; jt++)
#pragma unroll
        for (int qq = 0; qq < 4; qq++) cont[jt][qq] = 0.0f;

    const float* kbase = k + ((size_t)b * Sx) * Dm + h * DH;
    for (int d4 = 0; d4 < 16; d4++) {
        float4 q0 = ((const float4*)qu[0])[d4];
        float4 q1 = ((const float4*)qu[1])[d4];
        float4 q2 = ((const float4*)qu[2])[d4];
        float4 q3 = ((const float4*)qu[3])[d4];
#pragma unroll
        for (int jt = 0; jt < 8; jt++) {
            int j = tid + jt * 256;
            float4 kk = *(const float4*)(kbase + (size_t)j * Dm + d4 * 4);
            cont[jt][0] += q0.x * kk.x + q0.y * kk.y + q0.z * kk.z + q0.w * kk.w;
            cont[jt][1] += q1.x * kk.x + q1.y * kk.y + q1.z * kk.z + q1.w * kk.w;
            cont[jt][2] += q2.x * kk.x + q2.y * kk.y + q2.z * kk.z + q2.w * kk.w;
            cont[jt][3] += q3.x * kk.x + q3.y * kk.y + q3.z * kk.z + q3.w * kk.w;
        }
    }

    // ---- raw position scores into U[rr*2048 + r] = qv[rr] . p_r
    {
        float pa[8][5];
#pragma unroll
        for (int rt = 0; rt < 8; rt++)
#pragma unroll
            for (int rr = 0; rr < 5; rr++) pa[rt][rr] = 0.0f;
        const float* pbase = p + h * DH;
        for (int d4 = 0; d4 < 16; d4++) {
            float4 v0 = ((const float4*)qv[0])[d4];
            float4 v1 = ((const float4*)qv[1])[d4];
            float4 v2 = ((const float4*)qv[2])[d4];
            float4 v3 = ((const float4*)qv[3])[d4];
            float4 v4 = ((const float4*)qv[4])[d4];
#pragma unroll
            for (int rt = 0; rt < 8; rt++) {
                int r = tid + rt * 256;
                float4 pv = *(const float4*)(pbase + (size_t)r * Dm + d4 * 4);
                pa[rt][0] += v0.x * pv.x + v0.y * pv.y + v0.z * pv.z + v0.w * pv.w;
                pa[rt][1] += v1.x * pv.x + v1.y * pv.y + v1.z * pv.z + v1.w * pv.w;
                pa[rt][2] += v2.x * pv.x + v2.y * pv.y + v2.z * pv.z + v2.w * pv.w;
                pa[rt][3] += v3.x * pv.x + v3.y * pv.y + v3.z * pv.z + v3.w * pv.w;
                pa[rt][4] += v4.x * pv.x + v4.y * pv.y + v4.z * pv.z + v4.w * pv.w;
            }
        }
#pragma unroll
        for (int rt = 0; rt < 8; rt++) {
            int r = tid + rt * 256;
#pragma unroll
            for (int rr = 0; rr < 5; rr++) U[rr * Sx + r] = pa[rt][rr];
        }
    }
    __syncthreads();

    // ---- combine with relative shift; running max in registers
    const float scale = 0.125f;   // 64^-0.5
    float lmax[4] = {-1e30f, -1e30f, -1e30f, -1e30f};
#pragma unroll
    for (int jt = 0; jt < 8; jt++) {
        int j = tid + jt * 256;
#pragma unroll
        for (int qq = 0; qq < 4; qq++) {
            int i = i0 + qq;
            float pos;
            if (j <= i)        pos = U[qq * Sx + (Sx - 1 + j - i)];
            else if (j == i + 1) pos = 0.0f;
            else               pos = U[(qq + 1) * Sx + (j - i - 2)];
            float s2 = (cont[jt][qq] + pos) * scale;
            cont[jt][qq] = s2;
            lmax[qq] = fmaxf(lmax[qq], s2);
        }
    }

    float mred[4];
#pragma unroll
    for (int qq = 0; qq < 4; qq++) mred[qq] = block_reduce_max(lmax[qq], rbuf, tid);

    float lsum[4] = {0.0f, 0.0f, 0.0f, 0.0f};
#pragma unroll
    for (int jt = 0; jt < 8; jt++)
#pragma unroll
        for (int qq = 0; qq < 4; qq++) {
            float e = expf(cont[jt][qq] - mred[qq]);
            cont[jt][qq] = e;
            lsum[qq] += e;
        }
    float inv[4];
#pragma unroll
    for (int qq = 0; qq < 4; qq++) inv[qq] = 1.0f / block_reduce_sum(lsum[qq], rbuf, tid);

    // write probs (aliases the dead pos_raw region)
#pragma unroll
    for (int jt = 0; jt < 8; jt++) {
        int j = tid + jt * 256;
#pragma unroll
        for (int qq = 0; qq < 4; qq++) U[qq * Sx + j] = cont[jt][qq] * inv[qq];
    }
    __syncthreads();

    // ---- attn @ V
    int d = tid & 63, jg = tid >> 6;
    float a0 = 0, a1 = 0, a2 = 0, a3 = 0;
    const float* vb2 = v + ((size_t)b * Sx) * Dm + h * DH + d;
    int j0 = jg * 512;
    for (int j = j0; j < j0 + 512; j += 4) {
        float4 p0 = *(const float4*)&U[0 * Sx + j];
        float4 p1 = *(const float4*)&U[1 * Sx + j];
        float4 p2 = *(const float4*)&U[2 * Sx + j];
        float4 p3 = *(const float4*)&U[3 * Sx + j];
        float w0 = vb2[(size_t)(j + 0) * Dm];
        float w1 = vb2[(size_t)(j + 1) * Dm];
        float w2 = vb2[(size_t)(j + 2) * Dm];
        float w3 = vb2[(size_t)(j + 3) * Dm];
        a0 += p0.x * w0 + p0.y * w1 + p0.z * w2 + p0.w * w3;
        a1 += p1.x * w0 + p1.y * w1 + p1.z * w2 + p1.w * w3;
        a2 += p2.x * w0 + p2.y * w1 + p2.z * w2 + p2.w * w3;
        a3 += p3.x * w0 + p3.y * w1 + p3.z * w2 + p3.w * w3;
    }
    float* part = U + 4 * Sx;   // [4 groups][4 queries][64]
    part[(jg * 4 + 0) * 64 + d] = a0;
    part[(jg * 4 + 1) * 64 + d] = a1;
    part[(jg * 4 + 2) * 64 + d] = a2;
    part[(jg * 4 + 3) * 64 + d] = a3;
    __syncthreads();
    {
        int qq = tid >> 6, dd = tid & 63;
        float s2 = part[(0 * 4 + qq) * 64 + dd] + part[(1 * 4 + qq) * 64 + dd] +
                   part[(2 * 4 + qq) * 64 + dd] + part[(3 * 4 + qq) * 64 + dd];
        head[((size_t)(b * Sx + i0 + qq)) * Dm + h * DH + dd] = s2;
    }
}

// ---------------------------------------------------------------- launcher
extern "C" void kernel_launch(void* const* d_in, const int* in_sizes, int n_in,
                              void* d_out, int out_size, void* d_ws, size_t ws_size,
                              hipStream_t stream) {
    const float* x    = (const float*)d_in[0];
    const float* ln_g = (const float*)d_in[1];
    const float* ln_b = (const float*)d_in[2];
    const float* Wq   = (const float*)d_in[3];
    const float* bq   = (const float*)d_in[4];
    const float* Wk   = (const float*)d_in[5];
    const float* bk   = (const float*)d_in[6];
    const float* Wv   = (const float*)d_in[7];
    const float* bv   = (const float*)d_in[8];
    const float* Wp   = (const float*)d_in[9];
    const float* Wo   = (const float*)d_in[10];
    const float* bo   = (const float*)d_in[11];
    const float* ub   = (const float*)d_in[12];
    const float* vbias= (const float*)d_in[13];

    float* out = (float*)d_out;
    float* ws  = (float*)d_ws;

    const size_t MROWS = 2 * (size_t)Sx;          // 4096
    float* xn   = out;                            // alias: fully rewritten by final GEMM
    float* q    = ws;                             // 4M floats
    float* kbuf = ws + 4u  * 1024 * 1024;
    float* vbuf = ws + 8u  * 1024 * 1024;
    float* pe   = ws + 12u * 1024 * 1024;         // 2M floats
    float* pp   = ws + 14u * 1024 * 1024;         // 2M floats
    float* head = ws + 16u * 1024 * 1024;         // 4M floats -> 80MB total

    ln_kernel<<<(int)MROWS, 256, 0, stream>>>(x, ln_g, ln_b, xn);
    pe_kernel<<<Sx * 512 / 256, 256, 0, stream>>>(pe);

    dim3 g1(Dm / 128, (int)MROWS / 128);          // (8, 32)
    sgemm_kernel<<<g1, 256, 0, stream>>>(xn, Wq, bq, q,    (int)MROWS, Dm, Dm);
    sgemm_kernel<<<g1, 256, 0, stream>>>(xn, Wk, bk, kbuf, (int)MROWS, Dm, Dm);
    sgemm_kernel<<<g1, 256, 0, stream>>>(xn, Wv, bv, vbuf, (int)MROWS, Dm, Dm);
    dim3 g2(Dm / 128, Sx / 128);                  // (8, 16)
    sgemm_kernel<<<g2, 256, 0, stream>>>(pe, Wp, nullptr, pp, Sx, Dm, Dm);

    attn_kernel<<<2 * Hh * (Sx / 4), 256, 0, stream>>>(q, kbuf, vbuf, pp, ub, vbias, head);

    sgemm_kernel<<<g1, 256, 0, stream>>>(head, Wo, bo, out, (int)MROWS, Dm, Dm);
}